// Round 1
// baseline (274.620 us; speedup 1.0000x reference)
//
#include <hip/hip_runtime.h>
#include <hip/hip_bf16.h>

#define TPB 256
#define EPT 16
#define CHUNK (TPB * EPT)   // 4096 elements per block
#define P2T 1024            // single-block scan kernels

// ---------------------------------------------------------------------------
// Pass 1: per-element pre-shift compute + histograms + block sums + v bitmask
// ---------------------------------------------------------------------------
__global__ __launch_bounds__(TPB) void k_pass1(
    const float* __restrict__ blp, const int* __restrict__ st,
    const int* __restrict__ q, const int* __restrict__ fam,
    const int* __restrict__ mic, const int* __restrict__ vm,
    float* __restrict__ out_structural, float* __restrict__ combined_pre,
    unsigned long long* __restrict__ vbits,
    int* __restrict__ blocksum_v, double* __restrict__ blocksum_c,
    int* __restrict__ ghist, int n)
{
    __shared__ int lh[152];
    __shared__ double red_d[TPB];
    __shared__ int red_i[TPB];
    for (int t = threadIdx.x; t < 152; t += TPB) lh[t] = 0;
    __syncthreads();

    const long base = (long)blockIdx.x * CHUNK;
    int sv = 0;
    double sc = 0.0;

    #pragma unroll
    for (int k = 0; k < EPT; ++k) {
        long i = base + (long)k * TPB + threadIdx.x;
        int v = 0;
        if (i < n) {
            int sti = st[i], qi = q[i], fi = fam[i], mi = mic[i];
            v = (vm[i] != 0);
            float b = blp[i];
            int stn = 0, qn = 0, fn = 0;
            if (i + 1 < n) { stn = st[i + 1]; qn = q[i + 1]; fn = fam[i + 1]; }
            int om  = sti & 0xFFF; int c6  = ((om  >> 6) ^ om ) & 63;
            int omn = stn & 0xFFF; int c6n = ((omn >> 6) ^ omn) & 63;
            float d_chi = (float)__popc(c6 ^ c6n) * (1.0f / 6.0f);
            float d_q   = (float)__popc((qi & 63) ^ (qn & 63)) * (1.0f / 6.0f);
            int fx = (fi & 3) ^ (fn & 3);
            float d_fam = (float)((fx & 1) + ((fx >> 1) & 1)) * 0.5f;
            float score = 0.5f * d_chi + 0.35f * d_q + 0.15f * d_fam;
            score = fminf(fmaxf(score, 1e-6f), 1.0f);
            float structural = v ? score : 0.0f;
            float cosine = expf(fminf(b, 0.0f));
            float combined = 0.5f * (cosine + structural);  // (WC*c+WS*s)/1.0
            out_structural[i] = structural;
            combined_pre[i] = combined;
            if (v) {
                sv += 1;
                sc += (double)combined;
                atomicAdd(&lh[qi & 63], 1);              // q_hist64
                atomicAdd(&lh[64 + (fi & 3)], 1);        // family_hist4
                atomicAdd(&lh[68 + (mi & 63)], 1);       // micro_hist64
                atomicAdd(&lh[132 + __popc(c6)], 1);     // shell_hist7
                atomicAdd(&lh[139 + __popc(qi & 63)], 1);// q_weight_hist7
                int qb = qi & 63;
                #pragma unroll
                for (int j = 0; j < 6; ++j)
                    if ((qb >> j) & 1) atomicAdd(&lh[146 + j], 1); // bit_excitation6
            }
        }
        unsigned long long m = __ballot(v);
        long segstart = base + (long)k * TPB + (threadIdx.x & ~63);
        if ((threadIdx.x & 63) == 0 && segstart < n) vbits[segstart >> 6] = m;
    }

    red_i[threadIdx.x] = sv;
    red_d[threadIdx.x] = sc;
    __syncthreads();
    for (int off = TPB / 2; off > 0; off >>= 1) {
        if (threadIdx.x < off) {
            red_i[threadIdx.x] += red_i[threadIdx.x + off];
            red_d[threadIdx.x] += red_d[threadIdx.x + off];
        }
        __syncthreads();
    }
    if (threadIdx.x == 0) {
        blocksum_v[blockIdx.x] = red_i[0];
        blocksum_c[blockIdx.x] = red_d[0];
    }
    for (int t = threadIdx.x; t < 152; t += TPB)
        if (lh[t]) atomicAdd(&ghist[t], lh[t]);
}

// ---------------------------------------------------------------------------
// Pass 2: reduce block sums -> shift scalar; exclusive prefix of v counts;
//         emit histogram floats. Assumes nblocks <= P2T (n <= 4M: 1024 blocks)
// ---------------------------------------------------------------------------
__global__ __launch_bounds__(P2T) void k_pass2(
    const int* __restrict__ blocksum_v, const double* __restrict__ blocksum_c,
    int nblocks, int* __restrict__ pos_offset, float* __restrict__ shiftp,
    int* __restrict__ totalv_p, const int* __restrict__ ghist,
    float* __restrict__ out_hist)
{
    __shared__ int s[P2T];
    __shared__ double d[P2T];
    int tid = threadIdx.x;
    int v = (tid < nblocks) ? blocksum_v[tid] : 0;
    double c = (tid < nblocks) ? blocksum_c[tid] : 0.0;
    s[tid] = v; d[tid] = c;
    __syncthreads();
    for (int off = 1; off < P2T; off <<= 1) {       // inclusive scan (sum)
        int add = (tid >= off) ? s[tid - off] : 0;
        __syncthreads();
        s[tid] += add;
        __syncthreads();
    }
    if (tid < nblocks) pos_offset[tid] = s[tid] - v;
    for (int off = P2T / 2; off > 0; off >>= 1) {   // reduce doubles
        if (tid < off) d[tid] += d[tid + off];
        __syncthreads();
    }
    if (tid == 0) {
        int total_v = s[P2T - 1];
        *totalv_p = total_v;
        double vc = (double)(total_v > 1 ? total_v : 1);
        float cur = (float)(d[0] / vc);
        cur = fminf(fmaxf(cur, 1e-4f), 0.9999f);
        float p = fminf(fmaxf(cur, 1e-6f), 0.999999f);
        float lc = logf(p) - log1pf(-p);
        float tgt = (float)(1.0 / 6.0);             // 1/TARGET_BPP, clips no-op
        float lt = logf(tgt) - log1pf(-tgt);
        *shiftp = lt - lc;                          // GAIN = 1
    }
    if (tid < 152) out_hist[tid] = (float)ghist[tid];
}

// ---------------------------------------------------------------------------
// Pass 3a: apply shift -> logprobs + bmask outputs, pack bv bitmask
// ---------------------------------------------------------------------------
__global__ __launch_bounds__(TPB) void k_pass3a(
    const float* __restrict__ combined_pre,
    const unsigned long long* __restrict__ vbits,
    const float* __restrict__ shiftp,
    float* __restrict__ out_logp, float* __restrict__ out_bmask,
    unsigned long long* __restrict__ bvbits, int n)
{
    const float shift = *shiftp;
    const long base = (long)blockIdx.x * CHUNK;
    #pragma unroll
    for (int k = 0; k < EPT; ++k) {
        long i = base + (long)k * TPB + threadIdx.x;
        int bv = 0;
        if (i < n) {
            float cpre = combined_pre[i];
            float p = fminf(fmaxf(cpre, 1e-6f), 0.999999f);
            float z = logf(p) - log1pf(-p) + shift;
            float sgm = 1.0f / (1.0f + expf(-z));
            sgm = fminf(fmaxf(sgm, 1e-6f), 0.999999f);
            float clp = logf(sgm);
            out_logp[i] = clp;
            int bm = (clp >= -0.69314718f) ? 1 : 0;  // log(0.5) as f32
            out_bmask[i] = (float)bm;
            unsigned long long w = vbits[i >> 6];
            int vv = (int)((w >> (i & 63)) & 1ULL);
            bv = bm & vv;
        }
        unsigned long long mb = __ballot(bv);
        long segstart = base + (long)k * TPB + (threadIdx.x & ~63);
        if ((threadIdx.x & 63) == 0 && segstart < n) bvbits[segstart >> 6] = mb;
    }
}

// ---------------------------------------------------------------------------
// Pass 3b: per-block last-boundary-pos -> exclusive prefix max (carry);
//          trailing + patch_count scalars. Assumes nblocks <= P2T.
// ---------------------------------------------------------------------------
__global__ __launch_bounds__(P2T) void k_pass3b(
    const unsigned long long* __restrict__ vbits,
    const unsigned long long* __restrict__ bvbits,
    const int* __restrict__ pos_offset, const int* __restrict__ totalv_p,
    int nblocks, int nwords, int* __restrict__ carry,
    float* __restrict__ out_trailing, float* __restrict__ out_patch)
{
    __shared__ int s[P2T];
    __shared__ int cnts[P2T];
    int tid = threadIdx.x;
    int last_bpos = 0, cnt = 0;
    if (tid < nblocks) {
        long w0 = (long)tid * 64;
        int vacc = 0, u = -1;
        for (int w = 0; w < 64; ++w) {
            long wi = w0 + w;
            if (wi >= nwords) break;
            unsigned long long vb = vbits[wi], bb = bvbits[wi];
            if (bb) {
                int hb = 63 - __clzll(bb);
                u = vacc + __popcll(vb & (~0ULL >> (63 - hb)));
            }
            cnt += __popcll(bb);
            vacc += __popcll(vb);
        }
        if (u >= 0) last_bpos = pos_offset[tid] + u;
    }
    s[tid] = last_bpos; cnts[tid] = cnt;
    __syncthreads();
    for (int off = 1; off < P2T; off <<= 1) {       // inclusive max-scan
        int other = (tid >= off) ? s[tid - off] : 0;
        __syncthreads();
        if (other > s[tid]) s[tid] = other;
        __syncthreads();
    }
    if (tid < nblocks) carry[tid] = (tid > 0) ? s[tid - 1] : 0;
    int gmax = s[P2T - 1];
    __syncthreads();
    for (int off = P2T / 2; off > 0; off >>= 1) {
        if (tid < off) cnts[tid] += cnts[tid + off];
        __syncthreads();
    }
    if (tid == 0) {
        int total_v = *totalv_p;
        int trailing = total_v - gmax;
        int patch = cnts[0] + (trailing > 0 ? 1 : 0);
        *out_trailing = (float)trailing;
        *out_patch = (float)patch;
    }
}

// ---------------------------------------------------------------------------
// Pass 3c: dense run lengths from packed bitmasks
// ---------------------------------------------------------------------------
__global__ __launch_bounds__(TPB) void k_pass3c(
    const unsigned long long* __restrict__ vbits,
    const unsigned long long* __restrict__ bvbits,
    const int* __restrict__ pos_offset, const int* __restrict__ carry,
    float* __restrict__ out_len, int n)
{
    __shared__ unsigned long long s_vm[64], s_bm[64];
    __shared__ int s_base[64], s_prev[64];
    const int tid = threadIdx.x;
    const int b = blockIdx.x;
    const long w0 = (long)b * 64;
    const int nwords = (n + 63) >> 6;

    if (tid < 64) {
        long wi = w0 + tid;
        s_vm[tid] = (wi < nwords) ? vbits[wi] : 0ULL;
        s_bm[tid] = (wi < nwords) ? bvbits[wi] : 0ULL;
    }
    __syncthreads();

    if (tid < 64) {                                  // wave 0: segment scans
        int lane = tid;
        int vcnt = __popcll(s_vm[lane]);
        int x = vcnt;
        #pragma unroll
        for (int off = 1; off < 64; off <<= 1) {
            int y = __shfl_up(x, off, 64);
            if (lane >= off) x += y;
        }
        int basep = pos_offset[b] + (x - vcnt);      // exclusive v-prefix
        s_base[lane] = basep;
        unsigned long long bm = s_bm[lane];
        int lb = 0;
        if (bm) {
            int hb = 63 - __clzll(bm);
            lb = basep + __popcll(s_vm[lane] & (~0ULL >> (63 - hb)));
        }
        int m = lb;
        #pragma unroll
        for (int off = 1; off < 64; off <<= 1) {
            int y = __shfl_up(m, off, 64);
            if (lane >= off && y > m) m = y;
        }
        int exm = __shfl_up(m, 1, 64);
        if (lane == 0) exm = 0;
        int cb = carry[b];
        s_prev[lane] = exm > cb ? exm : cb;
    }
    __syncthreads();

    const int wv = tid >> 6, lane = tid & 63;
    #pragma unroll
    for (int k = 0; k < 16; ++k) {
        int seg = k * 4 + wv;
        long i = (w0 + seg) * 64 + lane;
        if (i < n) {
            unsigned long long vm = s_vm[seg], bm = s_bm[seg];
            float lenf = 0.0f;
            if ((bm >> lane) & 1ULL) {
                int pos = s_base[seg] + __popcll(vm & (~0ULL >> (63 - lane)));
                unsigned long long blt = lane ? (bm & (~0ULL >> (64 - lane))) : 0ULL;
                int prev;
                if (blt) {
                    int hb = 63 - __clzll(blt);
                    prev = s_base[seg] + __popcll(vm & (~0ULL >> (63 - hb)));
                } else {
                    prev = s_prev[seg];
                }
                lenf = (float)(pos - prev);
            }
            out_len[i] = lenf;
        }
    }
}

// ---------------------------------------------------------------------------
extern "C" void kernel_launch(void* const* d_in, const int* in_sizes, int n_in,
                              void* d_out, int out_size, void* d_ws, size_t ws_size,
                              hipStream_t stream)
{
    const float* blp = (const float*)d_in[0];
    const int* st   = (const int*)d_in[1];
    const int* q    = (const int*)d_in[2];
    const int* fam  = (const int*)d_in[3];
    const int* mic  = (const int*)d_in[4];
    const int* vm   = (const int*)d_in[5];
    const int n = in_sizes[0];
    const int nblocks = (n + CHUNK - 1) / CHUNK;     // 1024 for n=4M
    const int nwords = (n + 63) >> 6;

    float* out = (float*)d_out;
    float* out_logp       = out;
    float* out_bmask      = out + (size_t)n;
    float* out_structural = out + 2 * (size_t)n;
    float* out_hist       = out + 3 * (size_t)n;          // 152 floats
    float* out_len        = out + 3 * (size_t)n + 152;
    float* out_trailing   = out + 4 * (size_t)n + 152;
    float* out_patch      = out + 4 * (size_t)n + 153;
    float* combined_pre   = out_len;  // scratch; overwritten by pass 3c

    char* w = (char*)d_ws;
    int*    ghist      = (int*)(w);                    // 152 ints, zeroed below
    int*    blocksum_v = (int*)(w + 4096);
    int*    pos_offset = (int*)(w + 4096 + 16384);
    int*    carry      = (int*)(w + 4096 + 32768);
    float*  shiftp     = (float*)(w + 4096 + 49152);
    int*    totalv_p   = (int*)(w + 4096 + 49152 + 4);
    double* blocksum_c = (double*)(w + 57344);
    unsigned long long* vbits  = (unsigned long long*)(w + 90112);
    unsigned long long* bvbits = (unsigned long long*)(w + 90112 + (size_t)nwords * 8);

    hipMemsetAsync(ghist, 0, 1024, stream);

    k_pass1<<<dim3(nblocks), dim3(TPB), 0, stream>>>(
        blp, st, q, fam, mic, vm, out_structural, combined_pre,
        vbits, blocksum_v, blocksum_c, ghist, n);

    k_pass2<<<dim3(1), dim3(P2T), 0, stream>>>(
        blocksum_v, blocksum_c, nblocks, pos_offset, shiftp, totalv_p,
        ghist, out_hist);

    k_pass3a<<<dim3(nblocks), dim3(TPB), 0, stream>>>(
        combined_pre, vbits, shiftp, out_logp, out_bmask, bvbits, n);

    k_pass3b<<<dim3(1), dim3(P2T), 0, stream>>>(
        vbits, bvbits, pos_offset, totalv_p, nblocks, nwords, carry,
        out_trailing, out_patch);

    k_pass3c<<<dim3(nblocks), dim3(TPB), 0, stream>>>(
        vbits, bvbits, pos_offset, carry, out_len, n);
}

// Round 2
// 218.156 us; speedup vs baseline: 1.2588x; 1.2588x over previous
//
#include <hip/hip_runtime.h>
#include <hip/hip_bf16.h>

#define TPB 256
#define EPT 16
#define CHUNK (TPB * EPT)   // 4096 elements per block
#define P2T 1024            // single-block scan kernels

typedef unsigned long long ull;

// ---------------------------------------------------------------------------
// Pass 1: per-element pre-shift compute + histograms + block sums + v bitmask
// Histograms: 24 small bins via wave-ballot register accumulation (no atomics
// in the hot loop); q64/micro64 via per-wave LDS copies (within-wave atomics
// only).
// ---------------------------------------------------------------------------
__global__ __launch_bounds__(TPB) void k_pass1(
    const float* __restrict__ blp, const int* __restrict__ st,
    const int* __restrict__ q, const int* __restrict__ fam,
    const int* __restrict__ mic, const int* __restrict__ vm,
    float* __restrict__ out_structural, float* __restrict__ combined_pre,
    ull* __restrict__ vbits,
    int* __restrict__ blocksum_v, double* __restrict__ blocksum_c,
    int* __restrict__ ghist, int n)
{
    __shared__ int lh2[512];     // [0..255]: per-wave q64; [256..511]: per-wave micro64
    __shared__ int lhs[24];      // 0-3 fam, 4-10 shell, 11-17 wtq, 18-23 bits
    __shared__ double red_d[TPB];
    __shared__ int red_i[TPB];
    for (int t = threadIdx.x; t < 512; t += TPB) lh2[t] = 0;
    if (threadIdx.x < 24) lhs[threadIdx.x] = 0;
    __syncthreads();

    const long base = (long)blockIdx.x * CHUNK;
    const int wave = threadIdx.x >> 6;
    int sv = 0;
    double sc = 0.0;
    int hf[4] = {0,0,0,0};
    int hs7[7] = {0,0,0,0,0,0,0};
    int hw7[7] = {0,0,0,0,0,0,0};
    int hb6[6] = {0,0,0,0,0,0};

    #pragma unroll
    for (int k = 0; k < EPT; ++k) {
        long i = base + (long)k * TPB + threadIdx.x;
        int v = 0, qi = 0, fi = 0, shell = 0, wtq = 0;
        if (i < n) {
            int sti = st[i]; qi = q[i]; fi = fam[i]; int mi = mic[i];
            v = (vm[i] != 0);
            float b = blp[i];
            int stn = 0, qn = 0, fn = 0;
            if (i + 1 < n) { stn = st[i + 1]; qn = q[i + 1]; fn = fam[i + 1]; }
            int om  = sti & 0xFFF; int c6  = ((om  >> 6) ^ om ) & 63;
            int omn = stn & 0xFFF; int c6n = ((omn >> 6) ^ omn) & 63;
            float d_chi = (float)__popc(c6 ^ c6n) * (1.0f / 6.0f);
            float d_q   = (float)__popc((qi & 63) ^ (qn & 63)) * (1.0f / 6.0f);
            int fx = (fi & 3) ^ (fn & 3);
            float d_fam = (float)((fx & 1) + ((fx >> 1) & 1)) * 0.5f;
            float score = 0.5f * d_chi + 0.35f * d_q + 0.15f * d_fam;
            score = fminf(fmaxf(score, 1e-6f), 1.0f);
            float structural = v ? score : 0.0f;
            float cosine = expf(fminf(b, 0.0f));
            float combined = 0.5f * (cosine + structural);  // (WC*c+WS*s)/1.0
            out_structural[i] = structural;
            combined_pre[i] = combined;
            shell = __popc(c6);
            wtq = __popc(qi & 63);
            if (v) {
                sv += 1;
                sc += (double)combined;
                atomicAdd(&lh2[wave * 64 + (qi & 63)], 1);
                atomicAdd(&lh2[256 + wave * 64 + (mi & 63)], 1);
            }
        }
        ull m = __ballot(v);
        long segstart = base + (long)k * TPB + (threadIdx.x & ~63);
        if ((threadIdx.x & 63) == 0 && segstart < n) vbits[segstart >> 6] = m;
        // wave-aggregated small histograms (counts are wave-uniform)
        #pragma unroll
        for (int b2 = 0; b2 < 4; ++b2)
            hf[b2] += (int)__popcll(__ballot(v && ((fi & 3) == b2)));
        #pragma unroll
        for (int b2 = 0; b2 < 7; ++b2)
            hs7[b2] += (int)__popcll(__ballot(v && (shell == b2)));
        #pragma unroll
        for (int b2 = 0; b2 < 7; ++b2)
            hw7[b2] += (int)__popcll(__ballot(v && (wtq == b2)));
        #pragma unroll
        for (int j = 0; j < 6; ++j)
            hb6[j] += (int)__popcll(__ballot(v && (((qi >> j) & 1) != 0)));
    }

    if ((threadIdx.x & 63) == 0) {
        #pragma unroll
        for (int b2 = 0; b2 < 4; ++b2) if (hf[b2])  atomicAdd(&lhs[b2], hf[b2]);
        #pragma unroll
        for (int b2 = 0; b2 < 7; ++b2) if (hs7[b2]) atomicAdd(&lhs[4 + b2], hs7[b2]);
        #pragma unroll
        for (int b2 = 0; b2 < 7; ++b2) if (hw7[b2]) atomicAdd(&lhs[11 + b2], hw7[b2]);
        #pragma unroll
        for (int j = 0; j < 6; ++j)  if (hb6[j])  atomicAdd(&lhs[18 + j], hb6[j]);
    }

    red_i[threadIdx.x] = sv;
    red_d[threadIdx.x] = sc;
    __syncthreads();
    for (int off = TPB / 2; off > 0; off >>= 1) {
        if (threadIdx.x < off) {
            red_i[threadIdx.x] += red_i[threadIdx.x + off];
            red_d[threadIdx.x] += red_d[threadIdx.x + off];
        }
        __syncthreads();
    }
    if (threadIdx.x == 0) {
        blocksum_v[blockIdx.x] = red_i[0];
        blocksum_c[blockIdx.x] = red_d[0];
    }

    // global merge of all 152 bins
    for (int t = threadIdx.x; t < 152; t += TPB) {
        int val;
        if (t < 64)       val = lh2[t] + lh2[64 + t] + lh2[128 + t] + lh2[192 + t];
        else if (t < 68)  val = lhs[t - 64];
        else if (t < 132) { int b = t - 68; val = lh2[256 + b] + lh2[320 + b] + lh2[384 + b] + lh2[448 + b]; }
        else if (t < 139) val = lhs[4 + (t - 132)];
        else if (t < 146) val = lhs[11 + (t - 139)];
        else              val = lhs[18 + (t - 146)];
        if (val) atomicAdd(&ghist[t], val);
    }
}

// ---------------------------------------------------------------------------
// Pass 2: reduce block sums -> shift scalar; exclusive prefix of v counts;
//         emit histogram floats. Assumes nblocks <= P2T.
// ---------------------------------------------------------------------------
__global__ __launch_bounds__(P2T) void k_pass2(
    const int* __restrict__ blocksum_v, const double* __restrict__ blocksum_c,
    int nblocks, int* __restrict__ pos_offset, float* __restrict__ shiftp,
    int* __restrict__ totalv_p, const int* __restrict__ ghist,
    float* __restrict__ out_hist)
{
    __shared__ int s[P2T];
    __shared__ double d[P2T];
    int tid = threadIdx.x;
    int v = (tid < nblocks) ? blocksum_v[tid] : 0;
    double c = (tid < nblocks) ? blocksum_c[tid] : 0.0;
    s[tid] = v; d[tid] = c;
    __syncthreads();
    for (int off = 1; off < P2T; off <<= 1) {       // inclusive scan (sum)
        int add = (tid >= off) ? s[tid - off] : 0;
        __syncthreads();
        s[tid] += add;
        __syncthreads();
    }
    if (tid < nblocks) pos_offset[tid] = s[tid] - v;
    for (int off = P2T / 2; off > 0; off >>= 1) {   // reduce doubles
        if (tid < off) d[tid] += d[tid + off];
        __syncthreads();
    }
    if (tid == 0) {
        int total_v = s[P2T - 1];
        *totalv_p = total_v;
        double vc = (double)(total_v > 1 ? total_v : 1);
        float cur = (float)(d[0] / vc);
        cur = fminf(fmaxf(cur, 1e-4f), 0.9999f);
        float p = fminf(fmaxf(cur, 1e-6f), 0.999999f);
        float lc = logf(p) - log1pf(-p);
        float tgt = (float)(1.0 / 6.0);             // 1/TARGET_BPP
        float lt = logf(tgt) - log1pf(-tgt);
        *shiftp = lt - lc;                          // GAIN = 1
    }
    if (tid < 152) out_hist[tid] = (float)ghist[tid];
}

// ---------------------------------------------------------------------------
// Pass 3a: apply shift -> logprobs + bmask outputs, pack bv bitmask,
//          AND emit per-chunk boundary stats (count, last-boundary valid idx)
//          so pass3b never re-reads the bitmasks.
// ---------------------------------------------------------------------------
__global__ __launch_bounds__(TPB) void k_pass3a(
    const float* __restrict__ combined_pre,
    const ull* __restrict__ vbits,
    const float* __restrict__ shiftp,
    float* __restrict__ out_logp, float* __restrict__ out_bmask,
    ull* __restrict__ bvbits,
    int* __restrict__ chunk_u, int* __restrict__ chunk_cnt, int n)
{
    __shared__ int s_vc[64], s_u[64], s_cnt[64];
    const float shift = *shiftp;
    const long base = (long)blockIdx.x * CHUNK;
    #pragma unroll
    for (int k = 0; k < EPT; ++k) {
        long i = base + (long)k * TPB + threadIdx.x;
        int bv = 0;
        ull w = 0;
        if (i < n) {
            float cpre = combined_pre[i];
            float p = fminf(fmaxf(cpre, 1e-6f), 0.999999f);
            float z = logf(p) - log1pf(-p) + shift;
            float sgm = 1.0f / (1.0f + expf(-z));
            sgm = fminf(fmaxf(sgm, 1e-6f), 0.999999f);
            float clp = logf(sgm);
            out_logp[i] = clp;
            int bm = (clp >= -0.69314718f) ? 1 : 0;  // log(0.5)
            out_bmask[i] = (float)bm;
            w = vbits[i >> 6];
            int vv = (int)((w >> (i & 63)) & 1ULL);
            bv = bm & vv;
        }
        ull mb = __ballot(bv);
        int seg = k * 4 + (threadIdx.x >> 6);
        long segstart = base + (long)k * TPB + (threadIdx.x & ~63);
        if ((threadIdx.x & 63) == 0) {
            if (segstart < n) bvbits[segstart >> 6] = mb;
            s_vc[seg] = (segstart < n) ? (int)__popcll(w) : 0;
            s_cnt[seg] = (int)__popcll(mb);
            // valid-count up to & including the highest boundary bit
            s_u[seg] = mb ? (int)__popcll(w & (~0ULL >> __clzll(mb))) : -1;
        }
    }
    __syncthreads();
    if (threadIdx.x < 64) {
        int lane = threadIdx.x;
        int vc = s_vc[lane];
        int x = vc;
        #pragma unroll
        for (int off = 1; off < 64; off <<= 1) {
            int y = __shfl_up(x, off, 64);
            if (lane >= off) x += y;
        }
        int vpre = x - vc;                       // exclusive valid prefix in chunk
        int u = s_u[lane];
        int lb = (u >= 0) ? vpre + u : -1;       // last boundary's valid idx (later segs dominate)
        int cnt = s_cnt[lane];
        #pragma unroll
        for (int off = 32; off > 0; off >>= 1) {
            int lb2 = __shfl_down(lb, off, 64);
            if (lb2 > lb) lb = lb2;
            cnt += __shfl_down(cnt, off, 64);
        }
        if (lane == 0) {
            chunk_u[blockIdx.x] = lb;            // -1 if no boundary in chunk
            chunk_cnt[blockIdx.x] = cnt;
        }
    }
}

// ---------------------------------------------------------------------------
// Pass 3b: tiny scan over per-chunk stats -> carry / trailing / patch_count.
// Reads only ~12 KB. Assumes nblocks <= P2T.
// ---------------------------------------------------------------------------
__global__ __launch_bounds__(P2T) void k_pass3b(
    const int* __restrict__ chunk_u, const int* __restrict__ chunk_cnt,
    const int* __restrict__ pos_offset, const int* __restrict__ totalv_p,
    int nblocks, int* __restrict__ carry,
    float* __restrict__ out_trailing, float* __restrict__ out_patch)
{
    __shared__ int s[P2T];
    __shared__ int cnts[P2T];
    int tid = threadIdx.x;
    int u = (tid < nblocks) ? chunk_u[tid] : -1;
    int cnt = (tid < nblocks) ? chunk_cnt[tid] : 0;
    int last_bpos = (u >= 0) ? pos_offset[tid] + u : 0;
    s[tid] = last_bpos; cnts[tid] = cnt;
    __syncthreads();
    for (int off = 1; off < P2T; off <<= 1) {       // inclusive max-scan
        int other = (tid >= off) ? s[tid - off] : 0;
        __syncthreads();
        if (other > s[tid]) s[tid] = other;
        __syncthreads();
    }
    if (tid < nblocks) carry[tid] = (tid > 0) ? s[tid - 1] : 0;
    int gmax = s[P2T - 1];
    __syncthreads();
    for (int off = P2T / 2; off > 0; off >>= 1) {
        if (tid < off) cnts[tid] += cnts[tid + off];
        __syncthreads();
    }
    if (tid == 0) {
        int total_v = *totalv_p;
        int trailing = total_v - gmax;
        int patch = cnts[0] + (trailing > 0 ? 1 : 0);
        *out_trailing = (float)trailing;
        *out_patch = (float)patch;
    }
}

// ---------------------------------------------------------------------------
// Pass 3c: dense run lengths from packed bitmasks
// ---------------------------------------------------------------------------
__global__ __launch_bounds__(TPB) void k_pass3c(
    const ull* __restrict__ vbits,
    const ull* __restrict__ bvbits,
    const int* __restrict__ pos_offset, const int* __restrict__ carry,
    float* __restrict__ out_len, int n)
{
    __shared__ ull s_vm[64], s_bm[64];
    __shared__ int s_base[64], s_prev[64];
    const int tid = threadIdx.x;
    const int b = blockIdx.x;
    const long w0 = (long)b * 64;
    const int nwords = (n + 63) >> 6;

    if (tid < 64) {
        long wi = w0 + tid;
        s_vm[tid] = (wi < nwords) ? vbits[wi] : 0ULL;
        s_bm[tid] = (wi < nwords) ? bvbits[wi] : 0ULL;
    }
    __syncthreads();

    if (tid < 64) {                                  // wave 0: segment scans
        int lane = tid;
        int vcnt = (int)__popcll(s_vm[lane]);
        int x = vcnt;
        #pragma unroll
        for (int off = 1; off < 64; off <<= 1) {
            int y = __shfl_up(x, off, 64);
            if (lane >= off) x += y;
        }
        int basep = pos_offset[b] + (x - vcnt);      // exclusive v-prefix
        s_base[lane] = basep;
        ull bm = s_bm[lane];
        int lb = 0;
        if (bm) {
            lb = basep + (int)__popcll(s_vm[lane] & (~0ULL >> __clzll(bm)));
        }
        int m = lb;
        #pragma unroll
        for (int off = 1; off < 64; off <<= 1) {
            int y = __shfl_up(m, off, 64);
            if (lane >= off && y > m) m = y;
        }
        int exm = __shfl_up(m, 1, 64);
        if (lane == 0) exm = 0;
        int cb = carry[b];
        s_prev[lane] = exm > cb ? exm : cb;
    }
    __syncthreads();

    const int wv = tid >> 6, lane = tid & 63;
    #pragma unroll
    for (int k = 0; k < 16; ++k) {
        int seg = k * 4 + wv;
        long i = (w0 + seg) * 64 + lane;
        if (i < n) {
            ull vm = s_vm[seg], bm = s_bm[seg];
            float lenf = 0.0f;
            if ((bm >> lane) & 1ULL) {
                int pos = s_base[seg] + (int)__popcll(vm & (~0ULL >> (63 - lane)));
                ull blt = lane ? (bm & (~0ULL >> (64 - lane))) : 0ULL;
                int prev;
                if (blt) {
                    int hb = 63 - __clzll(blt);
                    prev = s_base[seg] + (int)__popcll(vm & (~0ULL >> (63 - hb)));
                } else {
                    prev = s_prev[seg];
                }
                lenf = (float)(pos - prev);
            }
            out_len[i] = lenf;
        }
    }
}

// ---------------------------------------------------------------------------
extern "C" void kernel_launch(void* const* d_in, const int* in_sizes, int n_in,
                              void* d_out, int out_size, void* d_ws, size_t ws_size,
                              hipStream_t stream)
{
    const float* blp = (const float*)d_in[0];
    const int* st   = (const int*)d_in[1];
    const int* q    = (const int*)d_in[2];
    const int* fam  = (const int*)d_in[3];
    const int* mic  = (const int*)d_in[4];
    const int* vm   = (const int*)d_in[5];
    const int n = in_sizes[0];
    const int nblocks = (n + CHUNK - 1) / CHUNK;     // 1024 for n=4M
    const int nwords = (n + 63) >> 6;

    float* out = (float*)d_out;
    float* out_logp       = out;
    float* out_bmask      = out + (size_t)n;
    float* out_structural = out + 2 * (size_t)n;
    float* out_hist       = out + 3 * (size_t)n;          // 152 floats
    float* out_len        = out + 3 * (size_t)n + 152;
    float* out_trailing   = out + 4 * (size_t)n + 152;
    float* out_patch      = out + 4 * (size_t)n + 153;
    float* combined_pre   = out_len;  // scratch; overwritten by pass 3c

    char* w = (char*)d_ws;
    int*    ghist      = (int*)(w);                        // 152 ints (memset)
    int*    blocksum_v = (int*)(w + 4096);
    int*    pos_offset = (int*)(w + 8192);
    int*    carry      = (int*)(w + 12288);
    int*    chunk_u    = (int*)(w + 16384);
    int*    chunk_cnt  = (int*)(w + 20480);
    float*  shiftp     = (float*)(w + 24576);
    int*    totalv_p   = (int*)(w + 24580);
    double* blocksum_c = (double*)(w + 28672);             // 8 KB
    ull*    vbits      = (ull*)(w + 40960);
    ull*    bvbits     = (ull*)(w + 40960 + (size_t)nwords * 8);

    hipMemsetAsync(ghist, 0, 1024, stream);

    k_pass1<<<dim3(nblocks), dim3(TPB), 0, stream>>>(
        blp, st, q, fam, mic, vm, out_structural, combined_pre,
        vbits, blocksum_v, blocksum_c, ghist, n);

    k_pass2<<<dim3(1), dim3(P2T), 0, stream>>>(
        blocksum_v, blocksum_c, nblocks, pos_offset, shiftp, totalv_p,
        ghist, out_hist);

    k_pass3a<<<dim3(nblocks), dim3(TPB), 0, stream>>>(
        combined_pre, vbits, shiftp, out_logp, out_bmask, bvbits,
        chunk_u, chunk_cnt, n);

    k_pass3b<<<dim3(1), dim3(P2T), 0, stream>>>(
        chunk_u, chunk_cnt, pos_offset, totalv_p, nblocks, carry,
        out_trailing, out_patch);

    k_pass3c<<<dim3(nblocks), dim3(TPB), 0, stream>>>(
        vbits, bvbits, pos_offset, carry, out_len, n);
}

// Round 3
// 210.993 us; speedup vs baseline: 1.3016x; 1.0339x over previous
//
#include <hip/hip_runtime.h>
#include <hip/hip_bf16.h>

#define TPB 256
#define EPT 8
#define CHUNK (TPB * EPT)   // 2048 elements per block
#define P2T 1024            // single-block scan kernels
#define MAXNB 2048

typedef unsigned long long ull;

__device__ __forceinline__ ull shfl_down_u64(ull x, int off) {
    unsigned lo = (unsigned)x, hi = (unsigned)(x >> 32);
    lo = __shfl_down(lo, off, 64);
    hi = __shfl_down(hi, off, 64);
    return ((ull)hi << 32) | lo;
}

// ---------------------------------------------------------------------------
// Pass 1: per-element pre-shift compute + histograms + block sums + v bitmask
// 8 contiguous elems/thread via int4/float4; packed-register small hists;
// per-wave LDS atomics only for q64/micro64.
// ---------------------------------------------------------------------------
__global__ __launch_bounds__(TPB, 4) void k_pass1(
    const float* __restrict__ blp, const int* __restrict__ st,
    const int* __restrict__ q, const int* __restrict__ fam,
    const int* __restrict__ mic, const int* __restrict__ vm,
    float* __restrict__ out_structural, float* __restrict__ combined_pre,
    ull* __restrict__ vbits, int* __restrict__ blocksum_v,
    double* __restrict__ blocksum_c, int* __restrict__ ghist, int n)
{
    __shared__ int lh2[512];     // per-wave q64 | per-wave micro64
    __shared__ int slhs[24];     // 0-3 fam, 4-10 shell, 11-17 wtq, 18-23 bits
    __shared__ int swv[4];
    __shared__ double swc[4];
    for (int t = threadIdx.x; t < 512; t += TPB) lh2[t] = 0;
    if (threadIdx.x < 24) slhs[threadIdx.x] = 0;
    __syncthreads();

    const int tid = threadIdx.x, lane = tid & 63, wave = tid >> 6;
    const long i0 = (long)blockIdx.x * CHUNK + (long)tid * EPT;
    const bool fastblk = ((long)(blockIdx.x + 1) * CHUNK <= n);

    int sv = 0;
    double sc = 0.0;
    ull accF = 0, accS0 = 0, accS1 = 0, accW0 = 0, accW1 = 0, accB = 0;
    unsigned mv = 0;

    int stv[9], qv[9], fv[9], micv[8], vmv[8];
    float bpv[8];

    if (fastblk) {
        int4 a, b;
        a = *(const int4*)(st + i0);  b = *(const int4*)(st + i0 + 4);
        stv[0]=a.x; stv[1]=a.y; stv[2]=a.z; stv[3]=a.w; stv[4]=b.x; stv[5]=b.y; stv[6]=b.z; stv[7]=b.w;
        a = *(const int4*)(q + i0);   b = *(const int4*)(q + i0 + 4);
        qv[0]=a.x; qv[1]=a.y; qv[2]=a.z; qv[3]=a.w; qv[4]=b.x; qv[5]=b.y; qv[6]=b.z; qv[7]=b.w;
        a = *(const int4*)(fam + i0); b = *(const int4*)(fam + i0 + 4);
        fv[0]=a.x; fv[1]=a.y; fv[2]=a.z; fv[3]=a.w; fv[4]=b.x; fv[5]=b.y; fv[6]=b.z; fv[7]=b.w;
        a = *(const int4*)(mic + i0); b = *(const int4*)(mic + i0 + 4);
        micv[0]=a.x; micv[1]=a.y; micv[2]=a.z; micv[3]=a.w; micv[4]=b.x; micv[5]=b.y; micv[6]=b.z; micv[7]=b.w;
        a = *(const int4*)(vm + i0);  b = *(const int4*)(vm + i0 + 4);
        vmv[0]=a.x; vmv[1]=a.y; vmv[2]=a.z; vmv[3]=a.w; vmv[4]=b.x; vmv[5]=b.y; vmv[6]=b.z; vmv[7]=b.w;
        float4 fa = *(const float4*)(blp + i0), fb = *(const float4*)(blp + i0 + 4);
        bpv[0]=fa.x; bpv[1]=fa.y; bpv[2]=fa.z; bpv[3]=fa.w; bpv[4]=fb.x; bpv[5]=fb.y; bpv[6]=fb.z; bpv[7]=fb.w;
        // neighbor element i0+8: next lane's first element (lane 63: guarded load)
        int nst = __shfl_down(stv[0], 1, 64);
        int nq  = __shfl_down(qv[0], 1, 64);
        int nf  = __shfl_down(fv[0], 1, 64);
        if (lane == 63) {
            nst = (i0 + 8 < n) ? st[i0 + 8] : 0;
            nq  = (i0 + 8 < n) ? q[i0 + 8] : 0;
            nf  = (i0 + 8 < n) ? fam[i0 + 8] : 0;
        }
        stv[8] = nst; qv[8] = nq; fv[8] = nf;
    } else {
        #pragma unroll
        for (int e = 0; e < 8; ++e) {
            long ii = i0 + e;
            bool r = ii < n;
            stv[e] = r ? st[ii] : 0;  qv[e] = r ? q[ii] : 0;  fv[e] = r ? fam[ii] : 0;
            micv[e] = r ? mic[ii] : 0; vmv[e] = r ? vm[ii] : 0; bpv[e] = r ? blp[ii] : 0.f;
        }
        stv[8] = (i0 + 8 < n) ? st[i0 + 8] : 0;
        qv[8]  = (i0 + 8 < n) ? q[i0 + 8] : 0;
        fv[8]  = (i0 + 8 < n) ? fam[i0 + 8] : 0;
    }

    float structural[8], combined[8];
    #pragma unroll
    for (int e = 0; e < 8; ++e) {
        int sti = stv[e], qi = qv[e], fi = fv[e], mi = micv[e];
        int v = (vmv[e] != 0);
        int om  = sti & 0xFFF;     int c6  = ((om  >> 6) ^ om ) & 63;
        int omn = stv[e+1] & 0xFFF; int c6n = ((omn >> 6) ^ omn) & 63;
        float d_chi = (float)__popc(c6 ^ c6n) * (1.0f / 6.0f);
        float d_q   = (float)__popc((qi & 63) ^ (qv[e+1] & 63)) * (1.0f / 6.0f);
        int fx = (fi & 3) ^ (fv[e+1] & 3);
        float d_fam = (float)((fx & 1) + ((fx >> 1) & 1)) * 0.5f;
        float score = 0.5f * d_chi + 0.35f * d_q + 0.15f * d_fam;
        score = fminf(fmaxf(score, 1e-6f), 1.0f);
        structural[e] = v ? score : 0.0f;
        float cosine = expf(fminf(bpv[e], 0.0f));
        combined[e] = 0.5f * (cosine + structural[e]);
        mv |= (unsigned)v << e;
        if (v) {
            sv += 1;
            sc += (double)combined[e];
            atomicAdd(&lh2[(wave << 6) + (qi & 63)], 1);
            atomicAdd(&lh2[256 + (wave << 6) + (mi & 63)], 1);
            accF += 1ULL << ((fi & 3) * 16);
            int sh = __popc(c6);
            ull ts = 1ULL << ((sh & 3) * 16);
            if (sh < 4) accS0 += ts; else accS1 += ts;
            int wq = __popc(qi & 63);
            ull tw = 1ULL << ((wq & 3) * 16);
            if (wq < 4) accW0 += tw; else accW1 += tw;
            accB += ((ull)(qi & 63) * 0x0000201008040201ULL) & 0x0004010040100401ULL;
        }
    }

    if (fastblk) {
        float4 o;
        o.x=structural[0]; o.y=structural[1]; o.z=structural[2]; o.w=structural[3];
        *(float4*)(out_structural + i0) = o;
        o.x=structural[4]; o.y=structural[5]; o.z=structural[6]; o.w=structural[7];
        *(float4*)(out_structural + i0 + 4) = o;
        o.x=combined[0]; o.y=combined[1]; o.z=combined[2]; o.w=combined[3];
        *(float4*)(combined_pre + i0) = o;
        o.x=combined[4]; o.y=combined[5]; o.z=combined[6]; o.w=combined[7];
        *(float4*)(combined_pre + i0 + 4) = o;
    } else {
        #pragma unroll
        for (int e = 0; e < 8; ++e)
            if (i0 + e < n) { out_structural[i0 + e] = structural[e]; combined_pre[i0 + e] = combined[e]; }
    }

    // assemble 64-bit v word from 8-bit per-lane masks (3 shuffle steps)
    {
        unsigned w32 = mv;
        unsigned t1 = __shfl_down(w32, 1, 64); w32 |= t1 << 8;
        unsigned t2 = __shfl_down(w32, 2, 64); w32 |= t2 << 16;
        unsigned t4 = __shfl_down(w32, 4, 64);
        ull w64 = (ull)w32 | ((ull)t4 << 32);
        if ((lane & 7) == 0 && i0 < n) vbits[i0 >> 6] = w64;
    }

    // wave reductions
    #pragma unroll
    for (int off = 32; off > 0; off >>= 1) {
        sv += __shfl_down(sv, off, 64);
        sc += __shfl_down(sc, off, 64);
        accF  += shfl_down_u64(accF, off);
        accS0 += shfl_down_u64(accS0, off);
        accS1 += shfl_down_u64(accS1, off);
        accW0 += shfl_down_u64(accW0, off);
        accW1 += shfl_down_u64(accW1, off);
        accB  += shfl_down_u64(accB, off);
    }
    if (lane == 0) {
        swv[wave] = sv; swc[wave] = sc;
        #pragma unroll
        for (int b2 = 0; b2 < 4; ++b2) atomicAdd(&slhs[b2],      (int)((accF  >> (16*b2)) & 0xFFFF));
        #pragma unroll
        for (int b2 = 0; b2 < 4; ++b2) atomicAdd(&slhs[4 + b2],  (int)((accS0 >> (16*b2)) & 0xFFFF));
        #pragma unroll
        for (int b2 = 0; b2 < 3; ++b2) atomicAdd(&slhs[8 + b2],  (int)((accS1 >> (16*b2)) & 0xFFFF));
        #pragma unroll
        for (int b2 = 0; b2 < 4; ++b2) atomicAdd(&slhs[11 + b2], (int)((accW0 >> (16*b2)) & 0xFFFF));
        #pragma unroll
        for (int b2 = 0; b2 < 3; ++b2) atomicAdd(&slhs[15 + b2], (int)((accW1 >> (16*b2)) & 0xFFFF));
        #pragma unroll
        for (int b2 = 0; b2 < 6; ++b2) atomicAdd(&slhs[18 + b2], (int)((accB  >> (10*b2)) & 0x3FF));
    }
    __syncthreads();
    if (tid == 0) {
        blocksum_v[blockIdx.x] = swv[0] + swv[1] + swv[2] + swv[3];
        blocksum_c[blockIdx.x] = swc[0] + swc[1] + swc[2] + swc[3];
    }
    for (int t2 = tid; t2 < 152; t2 += TPB) {
        int val;
        if (t2 < 64)        val = lh2[t2] + lh2[64 + t2] + lh2[128 + t2] + lh2[192 + t2];
        else if (t2 < 68)   val = slhs[t2 - 64];
        else if (t2 < 132) { int b2 = t2 - 68; val = lh2[256 + b2] + lh2[320 + b2] + lh2[384 + b2] + lh2[448 + b2]; }
        else if (t2 < 139)  val = slhs[4 + (t2 - 132)];
        else if (t2 < 146)  val = slhs[11 + (t2 - 139)];
        else                val = slhs[18 + (t2 - 146)];
        if (val) atomicAdd(&ghist[t2], val);
    }
}

// ---------------------------------------------------------------------------
// Pass 2: scan per-chunk valid counts (2/thread) -> pos_offset, totalv, shift;
//         emit histogram floats.
// ---------------------------------------------------------------------------
__global__ __launch_bounds__(P2T) void k_pass2(
    const int* __restrict__ bsv, const double* __restrict__ bsc, int nb,
    int* __restrict__ pos_offset, float* __restrict__ shiftp,
    int* __restrict__ totalv_p, const int* __restrict__ ghist,
    float* __restrict__ out_hist)
{
    __shared__ int s[P2T];
    __shared__ double d[P2T];
    int t = threadIdx.x;
    int c0 = 2 * t, c1 = 2 * t + 1;
    int v0 = (c0 < nb) ? bsv[c0] : 0;
    int v1 = (c1 < nb) ? bsv[c1] : 0;
    double x0 = (c0 < nb) ? bsc[c0] : 0.0;
    double x1 = (c1 < nb) ? bsc[c1] : 0.0;
    s[t] = v0 + v1; d[t] = x0 + x1;
    __syncthreads();
    for (int off = 1; off < P2T; off <<= 1) {
        int add = (t >= off) ? s[t - off] : 0;
        __syncthreads();
        s[t] += add;
        __syncthreads();
    }
    if (c0 < nb) pos_offset[c0] = s[t] - v0 - v1;
    if (c1 < nb) pos_offset[c1] = s[t] - v1;
    for (int off = P2T / 2; off > 0; off >>= 1) {
        if (t < off) d[t] += d[t + off];
        __syncthreads();
    }
    if (t == 0) {
        int total_v = s[P2T - 1];
        *totalv_p = total_v;
        double vc = (double)(total_v > 1 ? total_v : 1);
        float cur = (float)(d[0] / vc);
        cur = fminf(fmaxf(cur, 1e-4f), 0.9999f);
        float p = fminf(fmaxf(cur, 1e-6f), 0.999999f);
        float lc = logf(p) - log1pf(-p);
        float tgt = (float)(1.0 / 6.0);
        float lt = logf(tgt) - log1pf(-tgt);
        *shiftp = lt - lc;
    }
    if (t < 152) out_hist[t] = (float)ghist[t];
}

// ---------------------------------------------------------------------------
// Pass 3 (fused 3a+3c): shift -> logprobs/bmask outputs; in-block run lengths
// via wave scans; per-chunk stats for the tiny fix-up pass.
// ---------------------------------------------------------------------------
__global__ __launch_bounds__(TPB, 8) void k_pass3(
    const float* __restrict__ cpre, const ull* __restrict__ vbits,
    const float* __restrict__ shiftp, const int* __restrict__ pos_offset,
    float* __restrict__ out_logp, float* __restrict__ out_bmask,
    float* __restrict__ out_len, int* __restrict__ chunk_cnt,
    int* __restrict__ chunk_last, ull* __restrict__ chunk_first, int n)
{
    __shared__ int swt[4], swm[4], scnt[4];
    __shared__ ull sfirst[4];
    const int tid = threadIdx.x, lane = tid & 63, wave = tid >> 6;
    const long i0 = (long)blockIdx.x * CHUNK + (long)tid * EPT;
    const bool fastblk = ((long)(blockIdx.x + 1) * CHUNK <= n);
    const float shift = *shiftp;

    float cp[8];
    unsigned mv = 0, mb = 0;
    if (fastblk) {
        float4 c0 = *(const float4*)(cpre + i0), c1 = *(const float4*)(cpre + i0 + 4);
        cp[0]=c0.x; cp[1]=c0.y; cp[2]=c0.z; cp[3]=c0.w; cp[4]=c1.x; cp[5]=c1.y; cp[6]=c1.z; cp[7]=c1.w;
        ull w = vbits[i0 >> 6];
        mv = (unsigned)((w >> (i0 & 63)) & 0xFF);
    } else {
        #pragma unroll
        for (int e = 0; e < 8; ++e) cp[e] = (i0 + e < n) ? cpre[i0 + e] : 0.5f;
        if (i0 < n) {
            ull w = vbits[i0 >> 6];
            mv = (unsigned)((w >> (i0 & 63)) & 0xFF);
        }
    }

    float lp[8], bmf[8], lenv[8];
    #pragma unroll
    for (int e = 0; e < 8; ++e) {
        float p = fminf(fmaxf(cp[e], 1e-6f), 0.999999f);
        float z = logf(p) - log1pf(-p) + shift;
        float sgm = 1.0f / (1.0f + expf(-z));
        sgm = fminf(fmaxf(sgm, 1e-6f), 0.999999f);
        float clp = logf(sgm);
        lp[e] = clp;
        int bm = (clp >= -0.69314718f) ? 1 : 0;
        bmf[e] = (float)bm;
        if (bm && ((mv >> e) & 1)) mb |= 1u << e;
        lenv[e] = 0.0f;
    }
    if (fastblk) {
        float4 o;
        o.x=lp[0]; o.y=lp[1]; o.z=lp[2]; o.w=lp[3];   *(float4*)(out_logp + i0) = o;
        o.x=lp[4]; o.y=lp[5]; o.z=lp[6]; o.w=lp[7];   *(float4*)(out_logp + i0 + 4) = o;
        o.x=bmf[0]; o.y=bmf[1]; o.z=bmf[2]; o.w=bmf[3]; *(float4*)(out_bmask + i0) = o;
        o.x=bmf[4]; o.y=bmf[5]; o.z=bmf[6]; o.w=bmf[7]; *(float4*)(out_bmask + i0 + 4) = o;
    } else {
        #pragma unroll
        for (int e = 0; e < 8; ++e)
            if (i0 + e < n) { out_logp[i0 + e] = lp[e]; out_bmask[i0 + e] = bmf[e]; }
    }

    // phase A: block-wide exclusive valid-count prefix
    int tvc = __popc(mv);
    int x = tvc;
    #pragma unroll
    for (int off = 1; off < 64; off <<= 1) {
        int y = __shfl_up(x, off, 64);
        if (lane >= off) x += y;
    }
    if (lane == 63) swt[wave] = x;
    __syncthreads();
    int wb = pos_offset[blockIdx.x];
    for (int w2 = 0; w2 < wave; ++w2) wb += swt[w2];
    const int vbase = wb + (x - tvc);        // 1-indexed abs pos = vbase + incl_count

    // phase B: last-boundary max-scan + cnt/first reductions
    int last = -1;
    if (mb) {
        int hb = 31 - __clz(mb);
        last = vbase + __popc(mv & ((2u << hb) - 1));
    }
    int m = last;
    #pragma unroll
    for (int off = 1; off < 64; off <<= 1) {
        int y = __shfl_up(m, off, 64);
        if (lane >= off && y > m) m = y;
    }
    int exm = __shfl_up(m, 1, 64);
    if (lane == 0) exm = -1;
    if (lane == 63) swm[wave] = m;
    int cnt = __popc(mb);
    ull fp = ~0ULL;
    if (mb) {
        int lb = __ffs(mb) - 1;
        int fv2 = vbase + __popc(mv & ((2u << lb) - 1));
        fp = ((ull)(unsigned)(i0 + lb) << 32) | (unsigned)fv2;
    }
    #pragma unroll
    for (int off = 32; off > 0; off >>= 1) {
        cnt += __shfl_down(cnt, off, 64);
        ull fo = shfl_down_u64(fp, off);
        if (fo < fp) fp = fo;
    }
    if (lane == 0) { scnt[wave] = cnt; sfirst[wave] = fp; }
    __syncthreads();

    int prev = exm;
    for (int w2 = 0; w2 < wave; ++w2) if (swm[w2] > prev) prev = swm[w2];

    int run = 0;
    #pragma unroll
    for (int e = 0; e < 8; ++e) {
        run += (mv >> e) & 1;
        if ((mb >> e) & 1) {
            int pos = vbase + run;
            lenv[e] = (prev >= 0) ? (float)(pos - prev) : 0.0f;  // first-in-block fixed by pass4
            prev = pos;
        }
    }
    if (fastblk) {
        float4 o;
        o.x=lenv[0]; o.y=lenv[1]; o.z=lenv[2]; o.w=lenv[3]; *(float4*)(out_len + i0) = o;
        o.x=lenv[4]; o.y=lenv[5]; o.z=lenv[6]; o.w=lenv[7]; *(float4*)(out_len + i0 + 4) = o;
    } else {
        #pragma unroll
        for (int e = 0; e < 8; ++e)
            if (i0 + e < n) out_len[i0 + e] = lenv[e];
    }
    if (tid == 0) {
        int c = scnt[0] + scnt[1] + scnt[2] + scnt[3];
        int L = swm[0];
        if (swm[1] > L) L = swm[1];
        if (swm[2] > L) L = swm[2];
        if (swm[3] > L) L = swm[3];
        ull F = sfirst[0];
        if (sfirst[1] < F) F = sfirst[1];
        if (sfirst[2] < F) F = sfirst[2];
        if (sfirst[3] < F) F = sfirst[3];
        chunk_cnt[blockIdx.x] = c;
        chunk_last[blockIdx.x] = L;
        chunk_first[blockIdx.x] = F;
    }
}

// ---------------------------------------------------------------------------
// Pass 4: tiny scan over per-chunk stats -> first-boundary length fix-up,
// trailing, patch_count. 2 chunks/thread, nb <= 2048.
// ---------------------------------------------------------------------------
__global__ __launch_bounds__(P2T) void k_pass4(
    const int* __restrict__ chunk_cnt, const int* __restrict__ chunk_last,
    const ull* __restrict__ chunk_first, const int* __restrict__ totalv_p,
    int nb, float* __restrict__ out_len,
    float* __restrict__ out_trailing, float* __restrict__ out_patch)
{
    __shared__ int s[P2T];
    __shared__ int cs[P2T];
    int t = threadIdx.x;
    int c0 = 2 * t, c1 = 2 * t + 1;
    int a = 0, b = 0;
    if (c0 < nb) { int z = chunk_last[c0]; a = z > 0 ? z : 0; }
    if (c1 < nb) { int z = chunk_last[c1]; b = z > 0 ? z : 0; }
    int cnt = ((c0 < nb) ? chunk_cnt[c0] : 0) + ((c1 < nb) ? chunk_cnt[c1] : 0);
    s[t] = a > b ? a : b;
    cs[t] = cnt;
    __syncthreads();
    for (int off = 1; off < P2T; off <<= 1) {
        int y = (t >= off) ? s[t - off] : 0;
        __syncthreads();
        if (y > s[t]) s[t] = y;
        __syncthreads();
    }
    int excl = (t > 0) ? s[t - 1] : 0;
    int carry0 = excl;
    int carry1 = excl > a ? excl : a;
    if (c0 < nb) {
        ull F = chunk_first[c0];
        if (F != ~0ULL) {
            int fi = (int)(F >> 32);
            int fv2 = (int)(F & 0xFFFFFFFFu);
            out_len[fi] = (float)(fv2 - carry0);
        }
    }
    if (c1 < nb) {
        ull F = chunk_first[c1];
        if (F != ~0ULL) {
            int fi = (int)(F >> 32);
            int fv2 = (int)(F & 0xFFFFFFFFu);
            out_len[fi] = (float)(fv2 - carry1);
        }
    }
    int gmax = s[P2T - 1];
    __syncthreads();
    for (int off = P2T / 2; off > 0; off >>= 1) {
        if (t < off) cs[t] += cs[t + off];
        __syncthreads();
    }
    if (t == 0) {
        int total_v = *totalv_p;
        int trailing = total_v - gmax;
        int patch = cs[0] + (trailing > 0 ? 1 : 0);
        *out_trailing = (float)trailing;
        *out_patch = (float)patch;
    }
}

// ---------------------------------------------------------------------------
extern "C" void kernel_launch(void* const* d_in, const int* in_sizes, int n_in,
                              void* d_out, int out_size, void* d_ws, size_t ws_size,
                              hipStream_t stream)
{
    const float* blp = (const float*)d_in[0];
    const int* st   = (const int*)d_in[1];
    const int* q    = (const int*)d_in[2];
    const int* fam  = (const int*)d_in[3];
    const int* mic  = (const int*)d_in[4];
    const int* vm   = (const int*)d_in[5];
    const int n = in_sizes[0];
    const int nb = (n + CHUNK - 1) / CHUNK;          // 2048 for n=4M
    const int nwords = (n + 63) >> 6;

    float* out = (float*)d_out;
    float* out_logp       = out;
    float* out_bmask      = out + (size_t)n;
    float* out_structural = out + 2 * (size_t)n;
    float* out_hist       = out + 3 * (size_t)n;     // 152 floats
    float* out_len        = out + 3 * (size_t)n + 152;
    float* out_trailing   = out + 4 * (size_t)n + 152;
    float* out_patch      = out + 4 * (size_t)n + 153;
    float* combined_pre   = out_len;   // scratch; safely overwritten in pass3/4

    char* w = (char*)d_ws;
    int*    ghist      = (int*)(w);                  // 152 ints (memset)
    int*    blocksum_v = (int*)(w + 4096);           // 2048 ints
    int*    pos_offset = (int*)(w + 16384);          // 2048 ints
    int*    chunk_cnt  = (int*)(w + 32768);          // 2048 ints
    int*    chunk_last = (int*)(w + 40960);          // 2048 ints
    float*  shiftp     = (float*)(w + 49152);
    int*    totalv_p   = (int*)(w + 49156);
    double* blocksum_c = (double*)(w + 53248);       // 2048 doubles
    ull*    chunk_first= (ull*)(w + 69632);          // 2048 ulls
    ull*    vbits      = (ull*)(w + 86016);          // nwords ulls

    hipMemsetAsync(ghist, 0, 1024, stream);

    k_pass1<<<dim3(nb), dim3(TPB), 0, stream>>>(
        blp, st, q, fam, mic, vm, out_structural, combined_pre,
        vbits, blocksum_v, blocksum_c, ghist, n);

    k_pass2<<<dim3(1), dim3(P2T), 0, stream>>>(
        blocksum_v, blocksum_c, nb, pos_offset, shiftp, totalv_p,
        ghist, out_hist);

    k_pass3<<<dim3(nb), dim3(TPB), 0, stream>>>(
        combined_pre, vbits, shiftp, pos_offset, out_logp, out_bmask,
        out_len, chunk_cnt, chunk_last, chunk_first, n);

    k_pass4<<<dim3(1), dim3(P2T), 0, stream>>>(
        chunk_cnt, chunk_last, chunk_first, totalv_p, nb, out_len,
        out_trailing, out_patch);
}